// Round 2
// baseline (106.349 us; speedup 1.0000x reference)
//
#include <hip/hip_runtime.h>

// 2D RoPE: x (B=8, H=16, N=4096, C=128) fp32, out-of-place.
// R = 32. Quarters: x0=[0:32), x1=[32:64), x2=[64:96), x3=[96:128).
// y0 = x0*rcos - x1*rsin ; y1 = x0*rsin + x1*rcos   (row tables)
// y2 = x2*ccos - x3*csin ; y3 = x2*csin + x3*ccos   (col tables)
// row_cs/col_cs: (64, 32, 2) fp32, [..,0]=cos, [..,1]=sin.
//
// Table amortization: all 128 (b,h) planes share idx/table values for a
// given n. Each thread fixes (n, t), loads tables once into registers,
// loops over BH_PER_THREAD planes doing pure streaming R/W.

#define NPOS 4096           // GRID_H * GRID_W
#define F4_PER_ROW 32       // 128 floats / 4
#define BH 128              // B * H
#define BH_PER_THREAD 16
#define NCHUNK (BH / BH_PER_THREAD)   // 8

__global__ __launch_bounds__(256)
void rope2d_kernel(const float4* __restrict__ x,
                   const int*    __restrict__ idx,
                   const float4* __restrict__ row_cs,   // per pos: 16 float4 (64 floats)
                   const float4* __restrict__ col_cs,
                   float4*       __restrict__ out)
{
    const int g = blockIdx.x * 256 + threadIdx.x;     // [0, NCHUNK*NPOS*8)
    const int t     = g & 7;                          // float4 lane within quarter
    const int n     = (g >> 3) & (NPOS - 1);          // position
    const int chunk = g >> 15;                        // bh chunk [0, NCHUNK)

    const int id   = idx[n];
    const int prow = id >> 16;
    const int pcol = id & 0xffff;

    // rcs0 = (cos r, sin r, cos r+1, sin r+1), rcs1 = (cos r+2, sin r+2, cos r+3, sin r+3)
    const float4 rcs0 = row_cs[prow * 16 + t * 2];
    const float4 rcs1 = row_cs[prow * 16 + t * 2 + 1];
    const float4 ccs0 = col_cs[pcol * 16 + t * 2];
    const float4 ccs1 = col_cs[pcol * 16 + t * 2 + 1];

    long long base = ((long long)(chunk * BH_PER_THREAD) * NPOS + n) * F4_PER_ROW + t;
    const long long step = (long long)NPOS * F4_PER_ROW;   // one (b,h) plane in float4s

    #pragma unroll 4
    for (int i = 0; i < BH_PER_THREAD; ++i, base += step) {
        const float4 x0 = x[base];
        const float4 x1 = x[base + 8];
        const float4 x2 = x[base + 16];
        const float4 x3 = x[base + 24];

        float4 y0, y1, y2, y3;
        y0.x = x0.x * rcs0.x - x1.x * rcs0.y;   y1.x = x0.x * rcs0.y + x1.x * rcs0.x;
        y0.y = x0.y * rcs0.z - x1.y * rcs0.w;   y1.y = x0.y * rcs0.w + x1.y * rcs0.z;
        y0.z = x0.z * rcs1.x - x1.z * rcs1.y;   y1.z = x0.z * rcs1.y + x1.z * rcs1.x;
        y0.w = x0.w * rcs1.z - x1.w * rcs1.w;   y1.w = x0.w * rcs1.w + x1.w * rcs1.z;

        y2.x = x2.x * ccs0.x - x3.x * ccs0.y;   y3.x = x2.x * ccs0.y + x3.x * ccs0.x;
        y2.y = x2.y * ccs0.z - x3.y * ccs0.w;   y3.y = x2.y * ccs0.w + x3.y * ccs0.z;
        y2.z = x2.z * ccs1.x - x3.z * ccs1.y;   y3.z = x2.z * ccs1.y + x3.z * ccs1.x;
        y2.w = x2.w * ccs1.z - x3.w * ccs1.w;   y3.w = x2.w * ccs1.w + x3.w * ccs1.z;

        out[base]      = y0;
        out[base + 8]  = y1;
        out[base + 16] = y2;
        out[base + 24] = y3;
    }
}

extern "C" void kernel_launch(void* const* d_in, const int* in_sizes, int n_in,
                              void* d_out, int out_size, void* d_ws, size_t ws_size,
                              hipStream_t stream) {
    const float4* x      = (const float4*)d_in[0];
    const int*    idx    = (const int*)d_in[1];
    const float4* row_cs = (const float4*)d_in[2];
    const float4* col_cs = (const float4*)d_in[3];
    float4*       out    = (float4*)d_out;

    const int work_items = NCHUNK * NPOS * 8;   // 262144
    const int block = 256;
    const int grid = work_items / block;        // 1024

    rope2d_kernel<<<grid, block, 0, stream>>>(x, idx, row_cs, col_cs, out);
}

// Round 4
// 94.499 us; speedup vs baseline: 1.1254x; 1.1254x over previous
//
#include <hip/hip_runtime.h>

// 2D RoPE: x (B=8, H=16, N=4096, C=128) fp32, out-of-place.
// R = 32. Quarters: x0=[0:32), x1=[32:64), x2=[64:96), x3=[96:128).
// y0 = x0*rcos - x1*rsin ; y1 = x0*rsin + x1*rcos   (row tables)
// y2 = x2*ccos - x3*csin ; y3 = x2*csin + x3*ccos   (col tables)
// row_cs/col_cs: (64, 32, 2) fp32, [..,0]=cos, [..,1]=sin.
//
// R1 structure (contiguous, grid-stride) + non-temporal payload loads/stores
// (tables & idx stay cached) + compile-time trip count for MLP.
// nontemporal builtins need clang ext_vector_type, not HIP_vector_type.

typedef float fv4 __attribute__((ext_vector_type(4)));

#define NPOS 4096           // GRID_H * GRID_W
#define F4_PER_ROW 32       // 128 floats / 4
#define NBLOCK 2048
#define NTHREAD (NBLOCK * 256)          // 524288
#define TOTAL_ITEMS (8 * 16 * NPOS * 8) // rows * 8 = 4194304
#define ITERS (TOTAL_ITEMS / NTHREAD)   // 8

__global__ __launch_bounds__(256)
void rope2d_kernel(const fv4* __restrict__ x,
                   const int* __restrict__ idx,
                   const fv4* __restrict__ row_cs,   // per pos: 16 fv4 (64 floats)
                   const fv4* __restrict__ col_cs,
                   fv4*       __restrict__ out)
{
    const int tid0 = blockIdx.x * 256 + threadIdx.x;

    #pragma unroll 2
    for (int i = 0; i < ITERS; ++i) {
        const int g     = tid0 + i * NTHREAD;
        const int rowid = g >> 3;              // which (b,h,n) row
        const int t     = g & 7;               // float4 lane within quarter
        const int n     = rowid & (NPOS - 1);  // position

        const int id   = idx[n];
        const int prow = id >> 16;
        const int pcol = id & 0xffff;

        const int base = rowid * F4_PER_ROW + t;

        const fv4 x0 = __builtin_nontemporal_load(x + base);
        const fv4 x1 = __builtin_nontemporal_load(x + base + 8);
        const fv4 x2 = __builtin_nontemporal_load(x + base + 16);
        const fv4 x3 = __builtin_nontemporal_load(x + base + 24);

        // rcs0 = (cos r, sin r, cos r+1, sin r+1), rcs1 = (cos r+2, sin r+2, cos r+3, sin r+3)
        const fv4 rcs0 = row_cs[prow * 16 + t * 2];
        const fv4 rcs1 = row_cs[prow * 16 + t * 2 + 1];
        const fv4 ccs0 = col_cs[pcol * 16 + t * 2];
        const fv4 ccs1 = col_cs[pcol * 16 + t * 2 + 1];

        fv4 y0, y1, y2, y3;
        y0.x = x0.x * rcs0.x - x1.x * rcs0.y;   y1.x = x0.x * rcs0.y + x1.x * rcs0.x;
        y0.y = x0.y * rcs0.z - x1.y * rcs0.w;   y1.y = x0.y * rcs0.w + x1.y * rcs0.z;
        y0.z = x0.z * rcs1.x - x1.z * rcs1.y;   y1.z = x0.z * rcs1.y + x1.z * rcs1.x;
        y0.w = x0.w * rcs1.z - x1.w * rcs1.w;   y1.w = x0.w * rcs1.w + x1.w * rcs1.z;

        y2.x = x2.x * ccs0.x - x3.x * ccs0.y;   y3.x = x2.x * ccs0.y + x3.x * ccs0.x;
        y2.y = x2.y * ccs0.z - x3.y * ccs0.w;   y3.y = x2.y * ccs0.w + x3.y * ccs0.z;
        y2.z = x2.z * ccs1.x - x3.z * ccs1.y;   y3.z = x2.z * ccs1.y + x3.z * ccs1.x;
        y2.w = x2.w * ccs1.z - x3.w * ccs1.w;   y3.w = x2.w * ccs1.w + x3.w * ccs1.z;

        __builtin_nontemporal_store(y0, out + base);
        __builtin_nontemporal_store(y1, out + base + 8);
        __builtin_nontemporal_store(y2, out + base + 16);
        __builtin_nontemporal_store(y3, out + base + 24);
    }
}

extern "C" void kernel_launch(void* const* d_in, const int* in_sizes, int n_in,
                              void* d_out, int out_size, void* d_ws, size_t ws_size,
                              hipStream_t stream) {
    const fv4* x      = (const fv4*)d_in[0];
    const int* idx    = (const int*)d_in[1];
    const fv4* row_cs = (const fv4*)d_in[2];
    const fv4* col_cs = (const fv4*)d_in[3];
    fv4*       out    = (fv4*)d_out;

    rope2d_kernel<<<NBLOCK, 256, 0, stream>>>(x, idx, row_cs, col_cs, out);
}